// Round 2
// baseline (503.349 us; speedup 1.0000x reference)
//
#include <hip/hip_runtime.h>
#include <hip/hip_bf16.h>

// Problem constants (reference): B=64, N=256, S=16, HID=32, HEADS=8
#define BB 64
#define NN 256
#define SS 16
#define HH 32
#define KK 8      // heads
#define NROWPAIRS (BB*NN)          // 16384 (b,n) pairs
#define STATS_BLOCKS 2048

// ---- workspace layout (bytes) ----
// 0    : int mode        (0=int32 mask, 1=byte mask, 2=float mask)
// 4    : int countRows   (# valid (b,n) pairs)
// 64   : uchar valid[16384]
// 16448: float sx[16]
// 16512: float sx2[16]
// 16576: float b1c[32]
// 16704: float W1c[512]

// ---------------------------------------------------------------------------
// Kernel A: single block. Detect mask dtype, build valid[], count valid rows,
// zero the float accumulators (ws is poisoned 0xAA before every launch).
// ---------------------------------------------------------------------------
__global__ void prep_kernel(const void* __restrict__ mask_raw,
                            int* __restrict__ mode_out,
                            int* __restrict__ count_out,
                            unsigned char* __restrict__ valid,
                            float* __restrict__ sx,
                            float* __restrict__ sx2) {
    int tid = threadIdx.x;
    if (tid < 16) { sx[tid] = 0.0f; sx2[tid] = 0.0f; }

    __shared__ int s_flags[2];   // [0]=float pattern seen, [1]=bool pattern seen
    __shared__ int s_mode;
    __shared__ int s_count;
    if (tid < 2) s_flags[tid] = 0;
    if (tid == 0) s_count = 0;
    __syncthreads();

    // Scan first 16384 bytes as 4096 words (in-bounds for all 3 layouts).
    const unsigned int* w = (const unsigned int*)mask_raw;
    int f_float = 0, f_bool = 0;
    for (int i = tid; i < 4096; i += 1024) {
        unsigned int v = w[i];
        if (v == 0x3F800000u) f_float = 1;
        // a byte value of exactly 1 in a non-LSB position can only be
        // packed bool bytes (int 0/1 and float 0.0/1.0 never produce it)
        if (((v >> 8) & 0xFFu) == 1u || ((v >> 16) & 0xFFu) == 1u ||
            ((v >> 24) & 0xFFu) == 1u) f_bool = 1;
    }
    if (f_float) atomicOr(&s_flags[0], 1);
    if (f_bool)  atomicOr(&s_flags[1], 1);
    __syncthreads();
    if (tid == 0) {
        int mode = s_flags[1] ? 1 : (s_flags[0] ? 2 : 0);
        s_mode = mode;
        *mode_out = mode;
    }
    __syncthreads();
    int mode = s_mode;

    int localc = 0;
    for (int i = tid; i < NROWPAIRS; i += 1024) {
        int masked;
        if (mode == 1)      masked = ((const unsigned char*)mask_raw)[i] != 0;
        else if (mode == 2) masked = ((const float*)mask_raw)[i] != 0.0f;
        else                masked = ((const int*)mask_raw)[i] != 0;
        unsigned char v = (unsigned char)(masked ? 0 : 1);  // valid = !mask
        valid[i] = v;
        localc += v;
    }
    atomicAdd(&s_count, localc);
    __syncthreads();
    if (tid == 0) *count_out = s_count;
}

// ---------------------------------------------------------------------------
// Kernel B: masked sum / sum-of-squares per channel s.
// ---------------------------------------------------------------------------
__global__ __launch_bounds__(256) void stats_kernel(
        const float* __restrict__ stacks,
        const unsigned char* __restrict__ valid,
        float* __restrict__ sx, float* __restrict__ sx2) {
    int tid = threadIdx.x;
    float4 s1 = make_float4(0.f, 0.f, 0.f, 0.f);
    float4 s2 = make_float4(0.f, 0.f, 0.f, 0.f);

    for (int k = 0; k < NROWPAIRS / STATS_BLOCKS; ++k) {
        int chunk = blockIdx.x + k * STATS_BLOCKS;
        if (!valid[chunk]) continue;               // block-uniform branch
        const float4* p = (const float4*)stacks + (size_t)chunk * 1024;
        #pragma unroll
        for (int it = 0; it < 4; ++it) {
            float4 v = p[tid + it * 256];
            s1.x += v.x; s1.y += v.y; s1.z += v.z; s1.w += v.w;
            s2.x += v.x * v.x; s2.y += v.y * v.y;
            s2.z += v.z * v.z; s2.w += v.w * v.w;
        }
    }

    __shared__ float lds[8 * 256];   // [comp][tid]
    lds[0 * 256 + tid] = s1.x; lds[1 * 256 + tid] = s1.y;
    lds[2 * 256 + tid] = s1.z; lds[3 * 256 + tid] = s1.w;
    lds[4 * 256 + tid] = s2.x; lds[5 * 256 + tid] = s2.y;
    lds[6 * 256 + tid] = s2.z; lds[7 * 256 + tid] = s2.w;
    __syncthreads();

    if (tid < 32) {
        int kind = tid >> 4;          // 0 = sum, 1 = sum sq
        int s = tid & 15;
        int g = s >> 2, c = (s & 3) + kind * 4;
        float tot = 0.f;
        for (int i = 0; i < 64; ++i) tot += lds[c * 256 + (g + i * 4)];
        atomicAdd(kind ? &sx2[s] : &sx[s], tot);
    }
}

// ---------------------------------------------------------------------------
// Kernel C: fold BN into layer 1.
// ---------------------------------------------------------------------------
__global__ void weights_kernel(const float* __restrict__ gamma,
                               const float* __restrict__ beta,
                               const float* __restrict__ W1,
                               const float* __restrict__ b1,
                               const float* __restrict__ sx,
                               const float* __restrict__ sx2,
                               const int* __restrict__ count_rows,
                               float* __restrict__ W1c,
                               float* __restrict__ b1c) {
    __shared__ float s_scale[SS], s_shift[SS];
    int tid = threadIdx.x;
    if (tid < SS) {
        float cnt = (float)(*count_rows) * (float)NN;
        if (cnt < 1.0f) cnt = 1.0f;
        float mean = sx[tid] / cnt;
        float var  = sx2[tid] / cnt - mean * mean;
        float sc   = gamma[tid] / sqrtf(var + 1e-5f);
        s_scale[tid] = sc;
        s_shift[tid] = beta[tid] - mean * sc;
    }
    __syncthreads();
    if (tid < SS * HH) W1c[tid] = s_scale[tid >> 5] * W1[tid];
    if (tid < HH) {
        float acc = b1[tid];
        #pragma unroll
        for (int s = 0; s < SS; ++s) acc += s_shift[s] * W1[s * HH + tid];
        b1c[tid] = acc;
    }
}

// ---------------------------------------------------------------------------
// Kernel D (v2): per-chunk fused MLP, k-outer weight amortization.
// Block = 64 threads = one (b,n) chunk (256 rows); thread handles rows
// t, t+64, t+128, t+192 (R=4). x staged in LDS TRANSPOSED (xs[c][row],
// stride 256: reads conflict-free, writes 4-way on 64 writes = negligible).
// Weights loaded as float4 once per k-step per wave (uniform -> broadcast),
// ~200 weight-load instructions per 256 rows instead of ~800 per row.
// j-dimension split in halves to keep h[4][16]=64 VGPRs (occupancy ~9 wg/CU,
// LDS-limited at 16 KB/block).
// ---------------------------------------------------------------------------
__global__ __launch_bounds__(64) void mlp_kernel(
        const float* __restrict__ stacks,
        const unsigned char* __restrict__ valid,
        const float* __restrict__ W1c,
        const float* __restrict__ b1c,
        const float* __restrict__ W2,
        const float* __restrict__ b2,
        float* __restrict__ out) {
    int bid = blockIdx.x;
    int t = threadIdx.x;
    float4* outp = (float4*)out + (size_t)bid * 512;   // 256 rows x 2 float4

    if (!valid[bid]) {
        float4 z = make_float4(0.f, 0.f, 0.f, 0.f);
        #pragma unroll
        for (int it = 0; it < 8; ++it) outp[it * 64 + t] = z;
        return;
    }

    __shared__ float xs[SS * 256];   // transposed: xs[c*256 + row]
    const float4* xp = (const float4*)stacks + (size_t)bid * 1024;
    #pragma unroll
    for (int it = 0; it < 16; ++it) {
        float4 v = xp[it * 64 + t];          // coalesced
        int row = it * 16 + (t >> 2);
        int c0 = (t & 3) * 4;
        xs[(c0 + 0) * 256 + row] = v.x;
        xs[(c0 + 1) * 256 + row] = v.y;
        xs[(c0 + 2) * 256 + row] = v.z;
        xs[(c0 + 3) * 256 + row] = v.w;
    }
    __syncthreads();

    float4 b2v0 = ((const float4*)b2)[0];
    float4 b2v1 = ((const float4*)b2)[1];
    float y[4][8];
    #pragma unroll
    for (int r = 0; r < 4; ++r) {
        y[r][0] = b2v0.x; y[r][1] = b2v0.y; y[r][2] = b2v0.z; y[r][3] = b2v0.w;
        y[r][4] = b2v1.x; y[r][5] = b2v1.y; y[r][6] = b2v1.z; y[r][7] = b2v1.w;
    }

    #pragma unroll
    for (int half = 0; half < 2; ++half) {
        float hb[16];
        {
            const float4* bp = (const float4*)b1c + half * 4;
            #pragma unroll
            for (int q = 0; q < 4; ++q) {
                float4 v = bp[q];
                hb[q * 4 + 0] = v.x; hb[q * 4 + 1] = v.y;
                hb[q * 4 + 2] = v.z; hb[q * 4 + 3] = v.w;
            }
        }
        float h[4][16];
        #pragma unroll
        for (int r = 0; r < 4; ++r)
            #pragma unroll
            for (int j = 0; j < 16; ++j) h[r][j] = hb[j];

        #pragma unroll
        for (int k = 0; k < 16; ++k) {
            float wk[16];
            const float4* wp = (const float4*)W1c + k * 8 + half * 4;
            #pragma unroll
            for (int q = 0; q < 4; ++q) {
                float4 v = wp[q];
                wk[q * 4 + 0] = v.x; wk[q * 4 + 1] = v.y;
                wk[q * 4 + 2] = v.z; wk[q * 4 + 3] = v.w;
            }
            float xk[4];
            #pragma unroll
            for (int r = 0; r < 4; ++r) xk[r] = xs[k * 256 + t + 64 * r];
            #pragma unroll
            for (int r = 0; r < 4; ++r)
                #pragma unroll
                for (int j = 0; j < 16; ++j)
                    h[r][j] = fmaf(xk[r], wk[j], h[r][j]);
        }

        #pragma unroll
        for (int j = 0; j < 16; ++j) {
            const float4* w2p = (const float4*)W2 + (half * 16 + j) * 2;
            float4 a = w2p[0], b = w2p[1];
            float w2r[8] = {a.x, a.y, a.z, a.w, b.x, b.y, b.z, b.w};
            #pragma unroll
            for (int r = 0; r < 4; ++r) {
                float hr = fmaxf(h[r][j], 0.0f);
                #pragma unroll
                for (int i = 0; i < 8; ++i)
                    y[r][i] = fmaf(hr, w2r[i], y[r][i]);
            }
        }
    }

    #pragma unroll
    for (int r = 0; r < 4; ++r) {
        int row = t + 64 * r;
        outp[row * 2 + 0] = make_float4(y[r][0], y[r][1], y[r][2], y[r][3]);
        outp[row * 2 + 1] = make_float4(y[r][4], y[r][5], y[r][6], y[r][7]);
    }
}

extern "C" void kernel_launch(void* const* d_in, const int* in_sizes, int n_in,
                              void* d_out, int out_size, void* d_ws, size_t ws_size,
                              hipStream_t stream) {
    const float* stacks = (const float*)d_in[0];
    const void*  mask   = d_in[1];
    const float* gamma  = (const float*)d_in[2];
    const float* beta   = (const float*)d_in[3];
    const float* W1     = (const float*)d_in[4];
    const float* b1     = (const float*)d_in[5];
    const float* W2     = (const float*)d_in[6];
    const float* b2     = (const float*)d_in[7];
    float* out = (float*)d_out;

    char* ws = (char*)d_ws;
    int*           mode      = (int*)(ws + 0);
    int*           countRows = (int*)(ws + 4);
    unsigned char* valid     = (unsigned char*)(ws + 64);
    float*         sx        = (float*)(ws + 16448);
    float*         sx2       = (float*)(ws + 16512);
    float*         b1c       = (float*)(ws + 16576);
    float*         W1c       = (float*)(ws + 16704);

    prep_kernel<<<1, 1024, 0, stream>>>(mask, mode, countRows, valid, sx, sx2);
    stats_kernel<<<STATS_BLOCKS, 256, 0, stream>>>(stacks, valid, sx, sx2);
    weights_kernel<<<1, 512, 0, stream>>>(gamma, beta, W1, b1, sx, sx2,
                                          countRows, W1c, b1c);
    mlp_kernel<<<NROWPAIRS, 64, 0, stream>>>(stacks, valid, W1c, b1c, W2, b2, out);
}

// Round 3
// 487.541 us; speedup vs baseline: 1.0324x; 1.0324x over previous
//
#include <hip/hip_runtime.h>
#include <hip/hip_bf16.h>

// Problem constants (reference): B=64, N=256, S=16, HID=32, HEADS=8
#define BB 64
#define NN 256
#define SS 16
#define HH 32
#define KK 8      // heads
#define NROWPAIRS (BB*NN)          // 16384 (b,n) pairs
#define STATS_BLOCKS 2048

// ---- workspace layout (bytes) ----
// 0    : int mode        (0=int32 mask, 1=byte mask, 2=float mask)
// 4    : int countRows   (# valid (b,n) pairs)
// 64   : uchar valid[16384]
// 16448: float sx[16]
// 16512: float sx2[16]

// ---------------------------------------------------------------------------
// Kernel A: single block. Detect mask dtype, build valid[], count valid rows,
// zero the float accumulators (ws is poisoned 0xAA before every launch).
// ---------------------------------------------------------------------------
__global__ void prep_kernel(const void* __restrict__ mask_raw,
                            int* __restrict__ mode_out,
                            int* __restrict__ count_out,
                            unsigned char* __restrict__ valid,
                            float* __restrict__ sx,
                            float* __restrict__ sx2) {
    int tid = threadIdx.x;
    if (tid < 16) { sx[tid] = 0.0f; sx2[tid] = 0.0f; }

    __shared__ int s_flags[2];   // [0]=float pattern seen, [1]=bool pattern seen
    __shared__ int s_mode;
    __shared__ int s_count;
    if (tid < 2) s_flags[tid] = 0;
    if (tid == 0) s_count = 0;
    __syncthreads();

    // Scan first 16384 bytes as 4096 words (in-bounds for all 3 layouts).
    const unsigned int* w = (const unsigned int*)mask_raw;
    int f_float = 0, f_bool = 0;
    for (int i = tid; i < 4096; i += 1024) {
        unsigned int v = w[i];
        if (v == 0x3F800000u) f_float = 1;
        // a byte value of exactly 1 in a non-LSB position can only be
        // packed bool bytes (int 0/1 and float 0.0/1.0 never produce it)
        if (((v >> 8) & 0xFFu) == 1u || ((v >> 16) & 0xFFu) == 1u ||
            ((v >> 24) & 0xFFu) == 1u) f_bool = 1;
    }
    if (f_float) atomicOr(&s_flags[0], 1);
    if (f_bool)  atomicOr(&s_flags[1], 1);
    __syncthreads();
    if (tid == 0) {
        int mode = s_flags[1] ? 1 : (s_flags[0] ? 2 : 0);
        s_mode = mode;
        *mode_out = mode;
    }
    __syncthreads();
    int mode = s_mode;

    int localc = 0;
    for (int i = tid; i < NROWPAIRS; i += 1024) {
        int masked;
        if (mode == 1)      masked = ((const unsigned char*)mask_raw)[i] != 0;
        else if (mode == 2) masked = ((const float*)mask_raw)[i] != 0.0f;
        else                masked = ((const int*)mask_raw)[i] != 0;
        unsigned char v = (unsigned char)(masked ? 0 : 1);  // valid = !mask
        valid[i] = v;
        localc += v;
    }
    atomicAdd(&s_count, localc);
    __syncthreads();
    if (tid == 0) *count_out = s_count;
}

// ---------------------------------------------------------------------------
// Kernel B: masked sum / sum-of-squares per channel s.
// One (b,n) pair = 16KB chunk (256 m-rows x 16 floats) = 1024 float4.
// Block of 256 threads handles 8 chunks; skip is block-uniform.
// ---------------------------------------------------------------------------
__global__ __launch_bounds__(256) void stats_kernel(
        const float* __restrict__ stacks,
        const unsigned char* __restrict__ valid,
        float* __restrict__ sx, float* __restrict__ sx2) {
    int tid = threadIdx.x;
    float4 s1 = make_float4(0.f, 0.f, 0.f, 0.f);
    float4 s2 = make_float4(0.f, 0.f, 0.f, 0.f);

    for (int k = 0; k < NROWPAIRS / STATS_BLOCKS; ++k) {
        int chunk = blockIdx.x + k * STATS_BLOCKS;
        if (!valid[chunk]) continue;               // block-uniform branch
        const float4* p = (const float4*)stacks + (size_t)chunk * 1024;
        #pragma unroll
        for (int it = 0; it < 4; ++it) {
            float4 v = p[tid + it * 256];
            s1.x += v.x; s1.y += v.y; s1.z += v.z; s1.w += v.w;
            s2.x += v.x * v.x; s2.y += v.y * v.y;
            s2.z += v.z * v.z; s2.w += v.w * v.w;
        }
    }

    __shared__ float lds[8 * 256];   // [comp][tid]
    lds[0 * 256 + tid] = s1.x; lds[1 * 256 + tid] = s1.y;
    lds[2 * 256 + tid] = s1.z; lds[3 * 256 + tid] = s1.w;
    lds[4 * 256 + tid] = s2.x; lds[5 * 256 + tid] = s2.y;
    lds[6 * 256 + tid] = s2.z; lds[7 * 256 + tid] = s2.w;
    __syncthreads();

    if (tid < 32) {
        int kind = tid >> 4;          // 0 = sum, 1 = sum sq
        int s = tid & 15;
        int g = s >> 2, c = (s & 3) + kind * 4;
        float tot = 0.f;
        for (int i = 0; i < 64; ++i) tot += lds[c * 256 + (g + i * 4)];
        atomicAdd(kind ? &sx2[s] : &sx[s], tot);
    }
}

// ---------------------------------------------------------------------------
// Kernel C (fused fold + MLP): block = one (b,n) pair, thread = one m row.
// BN fold (scale/shift) computed per block into LDS from the global stats;
// x normalized per-thread; original W1/W2 (read-only, uniform index ->
// scalar s_load + broadcast). v1 register-resident structure: ~20 waves/CU,
// x via 4x float4, all weights via uniform loads.
// ---------------------------------------------------------------------------
__global__ __launch_bounds__(256) void mlp_kernel(
        const float* __restrict__ stacks,
        const unsigned char* __restrict__ valid,
        const float* __restrict__ gamma,
        const float* __restrict__ beta,
        const float* __restrict__ W1,
        const float* __restrict__ b1,
        const float* __restrict__ W2,
        const float* __restrict__ b2,
        const float* __restrict__ sx,
        const float* __restrict__ sx2,
        const int* __restrict__ count_rows,
        float* __restrict__ out) {
    int bid = blockIdx.x;
    int tid = threadIdx.x;
    size_t row = (size_t)bid * NN + tid;
    float4* outp = (float4*)out + row * 2;

    if (!valid[bid]) {                 // block-uniform: whole block exits
        float4 z = make_float4(0.f, 0.f, 0.f, 0.f);
        outp[0] = z; outp[1] = z;
        return;
    }

    __shared__ float s_scale[SS], s_shift[SS];
    if (tid < SS) {
        float cnt = (float)(*count_rows) * (float)NN;
        if (cnt < 1.0f) cnt = 1.0f;
        float mean = sx[tid] / cnt;
        float var  = sx2[tid] / cnt - mean * mean;
        float sc   = gamma[tid] / sqrtf(var + 1e-5f);
        s_scale[tid] = sc;
        s_shift[tid] = beta[tid] - mean * sc;
    }
    __syncthreads();

    const float4* xp = (const float4*)stacks + row * 4;
    float4 x0 = xp[0], x1 = xp[1], x2 = xp[2], x3 = xp[3];
    float x[SS] = { x0.x, x0.y, x0.z, x0.w,  x1.x, x1.y, x1.z, x1.w,
                    x2.x, x2.y, x2.z, x2.w,  x3.x, x3.y, x3.z, x3.w };
    float xn[SS];
    #pragma unroll
    for (int k = 0; k < SS; ++k)
        xn[k] = fmaf(x[k], s_scale[k], s_shift[k]);   // LDS broadcast reads

    float h[HH];
    #pragma unroll
    for (int j = 0; j < HH; ++j) h[j] = b1[j];        // uniform -> scalar
    #pragma unroll
    for (int k = 0; k < SS; ++k) {
        float xk = xn[k];
        #pragma unroll
        for (int j = 0; j < HH; ++j) h[j] = fmaf(xk, W1[k * HH + j], h[j]);
    }
    #pragma unroll
    for (int j = 0; j < HH; ++j) h[j] = fmaxf(h[j], 0.0f);

    float y[KK];
    #pragma unroll
    for (int i = 0; i < KK; ++i) y[i] = b2[i];
    #pragma unroll
    for (int j = 0; j < HH; ++j) {
        float hj = h[j];
        #pragma unroll
        for (int i = 0; i < KK; ++i) y[i] = fmaf(hj, W2[j * KK + i], y[i]);
    }

    outp[0] = make_float4(y[0], y[1], y[2], y[3]);
    outp[1] = make_float4(y[4], y[5], y[6], y[7]);
}

extern "C" void kernel_launch(void* const* d_in, const int* in_sizes, int n_in,
                              void* d_out, int out_size, void* d_ws, size_t ws_size,
                              hipStream_t stream) {
    const float* stacks = (const float*)d_in[0];
    const void*  mask   = d_in[1];
    const float* gamma  = (const float*)d_in[2];
    const float* beta   = (const float*)d_in[3];
    const float* W1     = (const float*)d_in[4];
    const float* b1     = (const float*)d_in[5];
    const float* W2     = (const float*)d_in[6];
    const float* b2     = (const float*)d_in[7];
    float* out = (float*)d_out;

    char* ws = (char*)d_ws;
    int*           mode      = (int*)(ws + 0);
    int*           countRows = (int*)(ws + 4);
    unsigned char* valid     = (unsigned char*)(ws + 64);
    float*         sx        = (float*)(ws + 16448);
    float*         sx2      = (float*)(ws + 16512);

    prep_kernel<<<1, 1024, 0, stream>>>(mask, mode, countRows, valid, sx, sx2);
    stats_kernel<<<STATS_BLOCKS, 256, 0, stream>>>(stacks, valid, sx, sx2);
    mlp_kernel<<<NROWPAIRS, 256, 0, stream>>>(stacks, valid, gamma, beta,
                                              W1, b1, W2, b2, sx, sx2,
                                              countRows, out);
}